// Round 4
// baseline (4186.769 us; speedup 1.0000x reference)
//
#include <hip/hip_runtime.h>

// Fused 2-layer GRU scan. B=256,T=1024,F=64,U=128.
// R11: layer-pipeline across 32 blocks. R10 post-mortem: within 16 CUs the
// per-SIMD floor is ~1400 cyc/step of matrix pipe (72 MFMA x 19.4); R9's
// 2480 cyc already overlaps pipes ~fully. The layers are a one-way stream
// (L2 at t needs only h1(t)), so: blocks 0-15 = layer1 producers (W1 in-loop
// + U1 = 18 MFMA/wave/step), publish 4KB h1 tiles to a ws ring with
// __threadfence + agent-scope release flag; blocks 16-31 = layer2 consumers
// (W2+U2 = 24 MFMA/wave/step), agent-scope acquire spin, h1 tiles read from
// global (prefetched 1 step ahead). Producer never waits (1024 slots);
// consumer lags ~2 steps. xw prepass deleted (saves 178us + 384MB traffic);
// ws need drops 192MB -> 64MB. Per-SIMD matrix work halves.

#define TT 1024
#define FF 64
#define G3 384
#define NB 16                                 // row blocks per layer
#define SLOT_BYTES 4096                       // 16x128 bf16 h1 tile
#define FLAG_BYTES ((size_t)NB * TT * 4)
#define PIPE_WS_BYTES (FLAG_BYTES + (size_t)NB * TT * SLOT_BYTES)  // ~64.07MB

typedef __attribute__((ext_vector_type(8))) __bf16 bf16x8;
typedef __attribute__((ext_vector_type(4))) float f32x4;

#define MFMA(a, b, c) __builtin_amdgcn_mfma_f32_16x16x32_bf16((a), (b), (c), 0, 0, 0)

__device__ __forceinline__ float sigf(float x) {
    return __builtin_amdgcn_rcpf(1.0f + __expf(-x));
}

__device__ __forceinline__ void wait_flag(const unsigned int* f) {
    while (__hip_atomic_load(f, __ATOMIC_ACQUIRE, __HIP_MEMORY_SCOPE_AGENT) == 0u)
        __builtin_amdgcn_s_sleep(1);
}

__global__ void flag_clear(unsigned int* f) {
    f[blockIdx.x * 256 + threadIdx.x] = 0u;
}

// ---- fused pipeline kernel: blocks 0-15 layer1, blocks 16-31 layer2 -------
__global__ __launch_bounds__(512)
__attribute__((amdgpu_waves_per_eu(2, 2)))
void gru_pipe(
    const float* __restrict__ x,  const float* __restrict__ W1,
    const float* __restrict__ U1, const float* __restrict__ b1,
    const float* __restrict__ W2, const float* __restrict__ U2,
    const float* __restrict__ b2, unsigned char* __restrict__ ws,
    float* __restrict__ out)
{
    const int tid  = threadIdx.x;
    const int wave = tid >> 6;
    const int lane = tid & 63;
    const int quad = lane >> 4;
    const int lc   = lane & 15;
    const int u    = wave * 16 + lc;          // owned unit column

    __shared__ __align__(16) __bf16 hs[2][16][136];   // h1s (prod) / h2s (cons)
    for (int i = tid; i < 2 * 16 * 136; i += 512)
        ((__bf16*)hs)[i] = (__bf16)0.f;

    unsigned int* flags_all = (unsigned int*)ws;
    unsigned char* slots_all = ws + FLAG_BYTES;

    if (blockIdx.x < NB) {
        // =================== PRODUCER: layer 1 ===========================
        const int bid  = blockIdx.x;
        const int row0 = bid * 16;
        unsigned int* flags = flags_all + (size_t)bid * TT;
        unsigned char* slotb = slots_all + (size_t)bid * TT * SLOT_BYTES;

        // weights: W1 (K=64) + U1 (K=128), 18 frags = 72 regs
        bf16x8 U1B[3][4], W1B[3][2];
#pragma unroll
        for (int g = 0; g < 3; g++) {
#pragma unroll
            for (int kt = 0; kt < 4; kt++) {
                bf16x8 a;
#pragma unroll
                for (int j = 0; j < 8; j++)
                    a[j] = (__bf16)U1[(kt * 32 + quad * 8 + j) * G3 + g * 128 + u];
                U1B[g][kt] = a;
            }
#pragma unroll
            for (int kt = 0; kt < 2; kt++) {
                bf16x8 a;
#pragma unroll
                for (int j = 0; j < 8; j++)
                    a[j] = (__bf16)W1[(kt * 32 + quad * 8 + j) * G3 + g * 128 + u];
                W1B[g][kt] = a;
            }
        }
        const float c1z  = b1[u] + b1[G3 + u];
        const float c1r  = b1[128 + u] + b1[G3 + 128 + u];
        const float b1ih = b1[256 + u];
        const float b1rh = b1[G3 + 256 + u];
        const f32x4 c1zq  = {c1z, c1z, c1z, c1z};
        const f32x4 c1rq  = {c1r, c1r, c1r, c1r};
        const f32x4 b1ihq = {b1ih, b1ih, b1ih, b1ih};
        const f32x4 b1rhq = {b1rh, b1rh, b1rh, b1rh};

        const float* xrow = x + (size_t)(row0 + lc) * (TT * FF) + quad * 8;
        // x prefetch (1 step ahead): regs for step about to run
        f32x4 xp[4];
        xp[0] = *(const f32x4*)(xrow);
        xp[1] = *(const f32x4*)(xrow + 4);
        xp[2] = *(const f32x4*)(xrow + 32);
        xp[3] = *(const f32x4*)(xrow + 36);

        const int pr = tid >> 5;              // publish row 0..15
        const int pc = (tid & 31) * 4;        // publish col 0..124 step 4

        float h1c[4] = {0, 0, 0, 0};
        __syncthreads();

#define PSTEP(T, PAR)                                                          \
    {                                                                          \
        if ((T) > 0) { /* publish h1(T-1) from hs[PAR^1] */                    \
            uint2 pv = *(const uint2*)&hs[PAR ^ 1][pr][pc];                    \
            *(uint2*)(slotb + (size_t)((T) - 1) * SLOT_BYTES + pr * 256 +      \
                      pc * 2) = pv;                                            \
        }                                                                      \
        bf16x8 xa0, xa1;                                                       \
        _Pragma("unroll") for (int j = 0; j < 4; j++) {                        \
            xa0[j] = (__bf16)xp[0][j]; xa0[j + 4] = (__bf16)xp[1][j];          \
            xa1[j] = (__bf16)xp[2][j]; xa1[j + 4] = (__bf16)xp[3][j];          \
        }                                                                      \
        if ((T) + 1 < TT) { /* prefetch x(T+1) */                              \
            const float* px = xrow + (size_t)((T) + 1) * FF;                   \
            xp[0] = *(const f32x4*)px;                                         \
            xp[1] = *(const f32x4*)(px + 4);                                   \
            xp[2] = *(const f32x4*)(px + 32);                                  \
            xp[3] = *(const f32x4*)(px + 36);                                  \
        }                                                                      \
        bf16x8 A1[4];                                                          \
        _Pragma("unroll") for (int kt = 0; kt < 4; kt++)                       \
            A1[kt] = *(const bf16x8*)&hs[PAR ^ 1][lc][kt * 32 + quad * 8];     \
        f32x4 z1  = MFMA(xa0, W1B[0][0], c1zq);                                \
        z1        = MFMA(xa1, W1B[0][1], z1);                                  \
        f32x4 r1  = MFMA(xa0, W1B[1][0], c1rq);                                \
        r1        = MFMA(xa1, W1B[1][1], r1);                                  \
        f32x4 xh1 = MFMA(xa0, W1B[2][0], b1ihq);                               \
        xh1       = MFMA(xa1, W1B[2][1], xh1);                                 \
        f32x4 rh1 = MFMA(A1[0], U1B[2][0], b1rhq);                             \
        z1        = MFMA(A1[0], U1B[0][0], z1);                                \
        r1        = MFMA(A1[0], U1B[1][0], r1);                                \
        _Pragma("unroll") for (int kt = 1; kt < 4; kt++) {                     \
            z1  = MFMA(A1[kt], U1B[0][kt], z1);                                \
            r1  = MFMA(A1[kt], U1B[1][kt], r1);                                \
            rh1 = MFMA(A1[kt], U1B[2][kt], rh1);                               \
        }                                                                      \
        _Pragma("unroll") for (int i = 0; i < 4; i++) {                        \
            float zf = sigf(z1[i]);                                            \
            float rf = sigf(r1[i]);                                            \
            float hh = fmaxf(xh1[i] + rf * rh1[i], 0.f);                       \
            h1c[i] = fmaf(zf, h1c[i] - hh, hh);                                \
            hs[PAR][quad * 4 + i][u] = (__bf16)h1c[i];                         \
        }                                                                      \
        __threadfence(); /* drain publish stores, agent-visible */             \
        asm volatile("s_waitcnt lgkmcnt(0)\n\ts_barrier" ::: "memory");        \
        if ((T) > 0 && tid == 0)                                               \
            __hip_atomic_store(flags + (T) - 1, 1u, __ATOMIC_RELEASE,          \
                               __HIP_MEMORY_SCOPE_AGENT);                      \
    }

        for (int t = 0; t < TT; t += 2) {
            PSTEP(t, 0)
            PSTEP(t + 1, 1)
        }
#undef PSTEP

        // epilogue: publish h1(TT-1) (lives in hs[1]) + final flag
        {
            uint2 pv = *(const uint2*)&hs[1][pr][pc];
            *(uint2*)(slotb + (size_t)(TT - 1) * SLOT_BYTES + pr * 256 + pc * 2) = pv;
            __threadfence();
            __syncthreads();
            if (tid == 0)
                __hip_atomic_store(flags + TT - 1, 1u, __ATOMIC_RELEASE,
                                   __HIP_MEMORY_SCOPE_AGENT);
        }
        // state1 = h1(TT-1)
#pragma unroll
        for (int i = 0; i < 4; i++) {
            int r = row0 + quad * 4 + i;
            out[32768 + (size_t)r * 128 + u] = h1c[i];
        }
    } else {
        // =================== CONSUMER: layer 2 ===========================
        const int bid  = blockIdx.x - NB;
        const int row0 = bid * 16;
        const unsigned int* flags = flags_all + (size_t)bid * TT;
        const unsigned char* slotb = slots_all + (size_t)bid * TT * SLOT_BYTES;

        bf16x8 W2B[3][4], U2B[3][4];
#pragma unroll
        for (int g = 0; g < 3; g++)
#pragma unroll
            for (int kt = 0; kt < 4; kt++) {
                bf16x8 b, c;
#pragma unroll
                for (int j = 0; j < 8; j++) {
                    int k = (kt * 32 + quad * 8 + j) * G3 + g * 128 + u;
                    b[j] = (__bf16)W2[k];
                    c[j] = (__bf16)U2[k];
                }
                W2B[g][kt] = b;
                U2B[g][kt] = c;
            }
        const float c2z  = b2[u] + b2[G3 + u];
        const float c2r  = b2[128 + u] + b2[G3 + 128 + u];
        const float b2ih = b2[256 + u];
        const float b2rh = b2[G3 + 256 + u];
        const f32x4 c2zq  = {c2z, c2z, c2z, c2z};
        const f32x4 c2rq  = {c2r, c2r, c2r, c2r};
        const f32x4 b2ihq = {b2ih, b2ih, b2ih, b2ih};
        const f32x4 b2rhq = {b2rh, b2rh, b2rh, b2rh};

        const unsigned char* abase = slotb + lc * 256 + quad * 16;
        float h2c[4] = {0, 0, 0, 0};
        __syncthreads();

        // prologue: wait slot 0, load A-frags for step 0
        wait_flag(flags);
        bf16x8 Aa0, Aa1, Aa2, Aa3, Ab0, Ab1, Ab2, Ab3;
        Aa0 = *(const bf16x8*)(abase);
        Aa1 = *(const bf16x8*)(abase + 64);
        Aa2 = *(const bf16x8*)(abase + 128);
        Aa3 = *(const bf16x8*)(abase + 192);

#define CSTEP(T, PAR, C0, C1, C2, C3, N0, N1, N2, N3)                          \
    {                                                                          \
        if ((T) + 1 < TT) { /* acquire + prefetch next h1 tile */              \
            wait_flag(flags + (T) + 1);                                        \
            const unsigned char* sp = abase + (size_t)((T) + 1) * SLOT_BYTES;  \
            N0 = *(const bf16x8*)(sp);                                         \
            N1 = *(const bf16x8*)(sp + 64);                                    \
            N2 = *(const bf16x8*)(sp + 128);                                   \
            N3 = *(const bf16x8*)(sp + 192);                                   \
        }                                                                      \
        f32x4 z2  = MFMA(C0, W2B[0][0], c2zq);                                 \
        f32x4 r2  = MFMA(C0, W2B[1][0], c2rq);                                 \
        f32x4 xh2 = MFMA(C0, W2B[2][0], b2ihq);                                \
        z2  = MFMA(C1, W2B[0][1], z2);                                         \
        r2  = MFMA(C1, W2B[1][1], r2);                                         \
        xh2 = MFMA(C1, W2B[2][1], xh2);                                        \
        z2  = MFMA(C2, W2B[0][2], z2);                                         \
        r2  = MFMA(C2, W2B[1][2], r2);                                         \
        xh2 = MFMA(C2, W2B[2][2], xh2);                                        \
        z2  = MFMA(C3, W2B[0][3], z2);                                         \
        r2  = MFMA(C3, W2B[1][3], r2);                                         \
        xh2 = MFMA(C3, W2B[2][3], xh2);                                        \
        f32x4 rh2;                                                             \
        {                                                                      \
            bf16x8 A2 = *(const bf16x8*)&hs[PAR ^ 1][lc][quad * 8];            \
            rh2 = MFMA(A2, U2B[2][0], b2rhq);                                  \
            z2  = MFMA(A2, U2B[0][0], z2);                                     \
            r2  = MFMA(A2, U2B[1][0], r2);                                     \
        }                                                                      \
        _Pragma("unroll") for (int kt = 1; kt < 4; kt++) {                     \
            bf16x8 A2 = *(const bf16x8*)&hs[PAR ^ 1][lc][kt * 32 + quad * 8];  \
            z2  = MFMA(A2, U2B[0][kt], z2);                                    \
            r2  = MFMA(A2, U2B[1][kt], r2);                                    \
            rh2 = MFMA(A2, U2B[2][kt], rh2);                                   \
        }                                                                      \
        _Pragma("unroll") for (int i = 0; i < 4; i++) {                        \
            float zf = sigf(z2[i]);                                            \
            float rf = sigf(r2[i]);                                            \
            float hh = fmaxf(xh2[i] + rf * rh2[i], 0.f);                       \
            h2c[i] = fmaf(zf, h2c[i] - hh, hh);                                \
            hs[PAR][quad * 4 + i][u] = (__bf16)h2c[i];                         \
        }                                                                      \
        asm volatile("s_waitcnt lgkmcnt(0)\n\ts_barrier" ::: "memory");        \
    }

        for (int t = 0; t < TT; t += 2) {
            CSTEP(t, 0, Aa0, Aa1, Aa2, Aa3, Ab0, Ab1, Ab2, Ab3)
            CSTEP(t + 1, 1, Ab0, Ab1, Ab2, Ab3, Aa0, Aa1, Aa2, Aa3)
        }
#undef CSTEP

        // out: x = h2(TT-1), state2 = h2(TT-1)
#pragma unroll
        for (int i = 0; i < 4; i++) {
            int r = row0 + quad * 4 + i;
            out[(size_t)r * 128 + u]         = h2c[i];
            out[65536 + (size_t)r * 128 + u] = h2c[i];
        }
    }
}

// ---- monolithic fallback (no workspace): R9 structure, W1 in-loop ---------
__global__ __launch_bounds__(512)
__attribute__((amdgpu_waves_per_eu(2, 2)))
void gru_mono(
    const float* __restrict__ x,  const float* __restrict__ W1,
    const float* __restrict__ U1, const float* __restrict__ b1,
    const float* __restrict__ W2, const float* __restrict__ U2,
    const float* __restrict__ b2, float* __restrict__ out)
{
    const int tid  = threadIdx.x;
    const int wave = tid >> 6;
    const int lane = tid & 63;
    const int quad = lane >> 4;
    const int lc   = lane & 15;
    const int row0 = blockIdx.x * 16;
    const int u    = wave * 16 + lc;

    __shared__ __align__(16) __bf16 h1s[2][16][136];
    __shared__ __align__(16) __bf16 h2s[2][16][136];
    for (int i = tid; i < 2 * 16 * 136; i += 512) {
        ((__bf16*)h1s)[i] = (__bf16)0.f;
        ((__bf16*)h2s)[i] = (__bf16)0.f;
    }

    bf16x8 U1B[3][4], W2B[3][4], U2B[3][4], W1B[3][2];
#pragma unroll
    for (int g = 0; g < 3; g++) {
#pragma unroll
        for (int kt = 0; kt < 4; kt++) {
            bf16x8 a, b, c;
#pragma unroll
            for (int j = 0; j < 8; j++) {
                int k = (kt * 32 + quad * 8 + j) * G3 + g * 128 + u;
                a[j] = (__bf16)U1[k];
                b[j] = (__bf16)W2[k];
                c[j] = (__bf16)U2[k];
            }
            U1B[g][kt] = a; W2B[g][kt] = b; U2B[g][kt] = c;
        }
#pragma unroll
        for (int kt = 0; kt < 2; kt++) {
            bf16x8 a;
#pragma unroll
            for (int j = 0; j < 8; j++)
                a[j] = (__bf16)W1[(kt * 32 + quad * 8 + j) * G3 + g * 128 + u];
            W1B[g][kt] = a;
        }
    }

    const float c1z  = b1[u] + b1[G3 + u];
    const float c1r  = b1[128 + u] + b1[G3 + 128 + u];
    const float b1ih = b1[256 + u];
    const float b1rh = b1[G3 + 256 + u];
    const float c2z  = b2[u] + b2[G3 + u];
    const float c2r  = b2[128 + u] + b2[G3 + 128 + u];
    const float b2ih = b2[256 + u];
    const float b2rh = b2[G3 + 256 + u];
    const f32x4 c1zq  = {c1z, c1z, c1z, c1z};
    const f32x4 c1rq  = {c1r, c1r, c1r, c1r};
    const f32x4 b1ihq = {b1ih, b1ih, b1ih, b1ih};
    const f32x4 b1rhq = {b1rh, b1rh, b1rh, b1rh};
    const f32x4 c2zq  = {c2z, c2z, c2z, c2z};
    const f32x4 c2rq  = {c2r, c2r, c2r, c2r};
    const f32x4 b2ihq = {b2ih, b2ih, b2ih, b2ih};
    const f32x4 b2rhq = {b2rh, b2rh, b2rh, b2rh};

    const float* xrow = x + (size_t)(row0 + lc) * (TT * FF) + quad * 8;
    float h1c[4] = {0, 0, 0, 0};
    float h2c[4] = {0, 0, 0, 0};
    __syncthreads();

#define MSTEP(T, PAR)                                                          \
    {                                                                          \
        bf16x8 A1[4];                                                          \
        _Pragma("unroll") for (int kt = 0; kt < 4; kt++)                       \
            A1[kt] = *(const bf16x8*)&h1s[PAR ^ 1][lc][kt * 32 + quad * 8];    \
        const float* px = xrow + (size_t)(T) * FF;                             \
        f32x4 u0 = *(const f32x4*)px;                                          \
        f32x4 u1 = *(const f32x4*)(px + 4);                                    \
        f32x4 u2 = *(const f32x4*)(px + 32);                                   \
        f32x4 u3 = *(const f32x4*)(px + 36);                                   \
        bf16x8 xa0, xa1;                                                       \
        _Pragma("unroll") for (int j = 0; j < 4; j++) {                        \
            xa0[j] = (__bf16)u0[j]; xa0[j + 4] = (__bf16)u1[j];                \
            xa1[j] = (__bf16)u2[j]; xa1[j + 4] = (__bf16)u3[j];                \
        }                                                                      \
        f32x4 z1  = MFMA(xa0, W1B[0][0], c1zq);                                \
        z1        = MFMA(xa1, W1B[0][1], z1);                                  \
        f32x4 r1  = MFMA(xa0, W1B[1][0], c1rq);                                \
        r1        = MFMA(xa1, W1B[1][1], r1);                                  \
        f32x4 xh1 = MFMA(xa0, W1B[2][0], b1ihq);                               \
        xh1       = MFMA(xa1, W1B[2][1], xh1);                                 \
        f32x4 rh1 = MFMA(A1[0], U1B[2][0], b1rhq);                             \
        z1        = MFMA(A1[0], U1B[0][0], z1);                                \
        r1        = MFMA(A1[0], U1B[1][0], r1);                                \
        _Pragma("unroll") for (int kt = 1; kt < 4; kt++) {                     \
            z1  = MFMA(A1[kt], U1B[0][kt], z1);                                \
            r1  = MFMA(A1[kt], U1B[1][kt], r1);                                \
            rh1 = MFMA(A1[kt], U1B[2][kt], rh1);                               \
        }                                                                      \
        _Pragma("unroll") for (int i = 0; i < 4; i++) {                        \
            float zf = sigf(z1[i]);                                            \
            float rf = sigf(r1[i]);                                            \
            float hh = fmaxf(xh1[i] + rf * rh1[i], 0.f);                       \
            h1c[i] = fmaf(zf, h1c[i] - hh, hh);                                \
            h1s[PAR][quad * 4 + i][u] = (__bf16)h1c[i];                        \
        }                                                                      \
        f32x4 z2  = MFMA(A1[0], W2B[0][0], c2zq);                              \
        f32x4 r2  = MFMA(A1[0], W2B[1][0], c2rq);                              \
        f32x4 xh2 = MFMA(A1[0], W2B[2][0], b2ihq);                             \
        _Pragma("unroll") for (int kt = 1; kt < 4; kt++) {                     \
            z2  = MFMA(A1[kt], W2B[0][kt], z2);                                \
            r2  = MFMA(A1[kt], W2B[1][kt], r2);                                \
            xh2 = MFMA(A1[kt], W2B[2][kt], xh2);                               \
        }                                                                      \
        f32x4 rh2;                                                             \
        {                                                                      \
            bf16x8 A2 = *(const bf16x8*)&h2s[PAR][lc][quad * 8];               \
            rh2 = MFMA(A2, U2B[2][0], b2rhq);                                  \
            z2  = MFMA(A2, U2B[0][0], z2);                                     \
            r2  = MFMA(A2, U2B[1][0], r2);                                     \
        }                                                                      \
        _Pragma("unroll") for (int kt = 1; kt < 4; kt++) {                     \
            bf16x8 A2 = *(const bf16x8*)&h2s[PAR][lc][kt * 32 + quad * 8];     \
            z2  = MFMA(A2, U2B[0][kt], z2);                                    \
            r2  = MFMA(A2, U2B[1][kt], r2);                                    \
            rh2 = MFMA(A2, U2B[2][kt], rh2);                                   \
        }                                                                      \
        if ((T) > 0) {                                                         \
            _Pragma("unroll") for (int i = 0; i < 4; i++) {                    \
                float zf = sigf(z2[i]);                                        \
                float rf = sigf(r2[i]);                                        \
                float hh = fmaxf(xh2[i] + rf * rh2[i], 0.f);                   \
                h2c[i] = fmaf(zf, h2c[i] - hh, hh);                            \
            }                                                                  \
        }                                                                      \
        _Pragma("unroll") for (int i = 0; i < 4; i++)                          \
            h2s[PAR ^ 1][quad * 4 + i][u] = (__bf16)h2c[i];                    \
        asm volatile("s_waitcnt lgkmcnt(0)\n\ts_barrier" ::: "memory");        \
    }

    for (int t = 0; t < TT; t += 2) {
        MSTEP(t, 0)
        MSTEP(t + 1, 1)
    }
#undef MSTEP

    {   // epilogue: h2(TT-1)
        f32x4 z2 = c2zq, r2 = c2rq, xh2 = b2ihq, rh2 = b2rhq;
#pragma unroll
        for (int kt = 0; kt < 4; kt++) {
            bf16x8 a1 = *(const bf16x8*)&h1s[1][lc][kt * 32 + quad * 8];
            bf16x8 a2 = *(const bf16x8*)&h2s[0][lc][kt * 32 + quad * 8];
            z2  = MFMA(a1, W2B[0][kt], z2);
            r2  = MFMA(a1, W2B[1][kt], r2);
            xh2 = MFMA(a1, W2B[2][kt], xh2);
            z2  = MFMA(a2, U2B[0][kt], z2);
            r2  = MFMA(a2, U2B[1][kt], r2);
            rh2 = MFMA(a2, U2B[2][kt], rh2);
        }
#pragma unroll
        for (int i = 0; i < 4; i++) {
            float zf = sigf(z2[i]);
            float rf = sigf(r2[i]);
            float hh = fmaxf(xh2[i] + rf * rh2[i], 0.f);
            h2c[i] = fmaf(zf, h2c[i] - hh, hh);
        }
    }

#pragma unroll
    for (int i = 0; i < 4; i++) {
        int r = row0 + quad * 4 + i;
        out[(size_t)r * 128 + u]         = h2c[i];
        out[32768 + (size_t)r * 128 + u] = h1c[i];
        out[65536 + (size_t)r * 128 + u] = h2c[i];
    }
}

extern "C" void kernel_launch(void* const* d_in, const int* in_sizes, int n_in,
                              void* d_out, int out_size, void* d_ws, size_t ws_size,
                              hipStream_t stream) {
    const float* x  = (const float*)d_in[0];
    const float* W1 = (const float*)d_in[1];
    const float* U1 = (const float*)d_in[2];
    const float* b1 = (const float*)d_in[3];
    const float* W2 = (const float*)d_in[4];
    const float* U2 = (const float*)d_in[5];
    const float* b2 = (const float*)d_in[6];
    float* out = (float*)d_out;

    if (ws_size >= PIPE_WS_BYTES) {
        unsigned char* ws = (unsigned char*)d_ws;
        flag_clear<<<dim3(NB * TT / 256), dim3(256), 0, stream>>>((unsigned int*)ws);
        gru_pipe<<<dim3(2 * NB), dim3(512), 0, stream>>>(
            x, W1, U1, b1, W2, U2, b2, ws, out);
    } else {
        gru_mono<<<dim3(NB), dim3(512), 0, stream>>>(
            x, W1, U1, b1, W2, U2, b2, out);
    }
}

// Round 5
// 2009.798 us; speedup vs baseline: 2.0832x; 2.0832x over previous
//
#include <hip/hip_runtime.h>

// Fused 2-layer GRU scan. B=256,T=1024,F=64,U=128.
// R12: in-block wave specialization. R11's cross-block pipe paid ~10k cyc/step
// in global handshake (threadfence+agent flags -> 66MB HBM writes); R10's
// phase rotation staggered nothing in time. This version keeps the single
// per-step s_barrier and specializes waves instead: 768 thr = 12 waves;
// waves 0-3 = layer1 (32 cols each, 24 MFMA/step), waves 4-11 = layer2
// (16 cols each, 24 MFMA/step), layer2 lagging one step so interval n
// computes h1(n) || h2(n-1) off LDS sealed by the previous barrier. Each
// SIMD now holds 1 L1 + 2 L2 waves with different phase mixes -> gate-VALU
// of one wave overlaps MFMA of the others (true time-stagger, not source
// rotation). Shared WB[2][3][4] keeps the L1/L2 weight-set union at 96 regs
// (U1-2cg == W2+U2-1cg == 24 frags) to fit the 170-reg cap at 3 waves/SIMD.

#define TT 1024
#define FF 64
#define G3 384
#define XW_BYTES (1024ull * 384 * 256 * 2)

typedef __attribute__((ext_vector_type(8))) __bf16 bf16x8;
typedef __attribute__((ext_vector_type(4))) float f32x4;

#define MFMA(a, b, c) __builtin_amdgcn_mfma_f32_16x16x32_bf16((a), (b), (c), 0, 0, 0)

__device__ __forceinline__ float sigf(float x) {
    return __builtin_amdgcn_rcpf(1.0f + __expf(-x));
}

__device__ __forceinline__ f32x4 unpackv(uint2 v) {
    f32x4 o;
    o[0] = __uint_as_float(v.x << 16);
    o[1] = __uint_as_float(v.x & 0xFFFF0000u);
    o[2] = __uint_as_float(v.y << 16);
    o[3] = __uint_as_float(v.y & 0xFFFF0000u);
    return o;
}

// ---- prepass: ws uint2 index = ((t*16+rb)*3+g)*512 + cg*64 + lane ---------
// slot holds batch rows quad*4..+3, unit col cg*16+lc, bf16x4 packed.
// Gates z,r carry BOTH biases; gate h only the input bias (b_rh separate).
__global__ void xw_prepass(
    const float* __restrict__ x, const float* __restrict__ W1,
    const float* __restrict__ b1, unsigned short* __restrict__ ws)
{
    const int tid = threadIdx.x, wave = tid >> 6, lane = tid & 63;
    const int quad = lane >> 4, lc = lane & 15;
    const int rb = blockIdx.x;              // row block (16 rows)
    const int t  = blockIdx.y * 4 + wave;   // time step

    const float* px = x + ((size_t)(rb * 16 + lc) * TT + t) * FF + quad * 8;
    f32x4 u0 = *(const f32x4*)px;
    f32x4 u1 = *(const f32x4*)(px + 4);
    f32x4 u2 = *(const f32x4*)(px + 32);
    f32x4 u3 = *(const f32x4*)(px + 36);
    bf16x8 xa0, xa1;
#pragma unroll
    for (int j = 0; j < 4; j++) {
        xa0[j] = (__bf16)u0[j]; xa0[j + 4] = (__bf16)u1[j];
        xa1[j] = (__bf16)u2[j]; xa1[j + 4] = (__bf16)u3[j];
    }

    uint2* wq = (uint2*)ws + ((size_t)t * 16 + rb) * 1536 + lane;
    for (int nt = 0; nt < 24; nt++) {
        const int g  = nt >> 3;
        const int cg = nt & 7;
        const int uc = cg * 16 + lc;
        float bi = b1[g * 128 + uc];
        if (g < 2) bi += b1[G3 + g * 128 + uc];
        bf16x8 w0, w1v;
#pragma unroll
        for (int j = 0; j < 8; j++) {
            w0[j]  = (__bf16)W1[(quad * 8 + j) * G3 + g * 128 + uc];
            w1v[j] = (__bf16)W1[(32 + quad * 8 + j) * G3 + g * 128 + uc];
        }
        f32x4 acc = {bi, bi, bi, bi};
        acc = MFMA(xa0, w0, acc);
        acc = MFMA(xa1, w1v, acc);
        unsigned int s0 = __builtin_bit_cast(unsigned short, (__bf16)acc[0]);
        unsigned int s1 = __builtin_bit_cast(unsigned short, (__bf16)acc[1]);
        unsigned int s2 = __builtin_bit_cast(unsigned short, (__bf16)acc[2]);
        unsigned int s3 = __builtin_bit_cast(unsigned short, (__bf16)acc[3]);
        uint2 st;
        st.x = s0 | (s1 << 16);
        st.y = s2 | (s3 << 16);
        wq[(size_t)(g * 8 + cg) * 64] = st;
    }
}

// ---- persistent scan: 12 waves, 0-3 layer1 (2cg), 4-11 layer2 (1cg) -------
__global__ __launch_bounds__(768)
__attribute__((amdgpu_waves_per_eu(3)))
void gru_persist(
    const float* __restrict__ U1, const float* __restrict__ b1,
    const float* __restrict__ W2, const float* __restrict__ U2,
    const float* __restrict__ b2, const unsigned short* __restrict__ xw,
    float* __restrict__ out)
{
    const int tid  = threadIdx.x;
    const int wave = tid >> 6;          // 0..11
    const int lane = tid & 63;
    const int quad = lane >> 4;
    const int lc   = lane & 15;
    const int row0 = blockIdx.x * 16;
    const bool isL1 = wave < 4;

    __shared__ __align__(16) __bf16 h1s[2][16][136];
    __shared__ __align__(16) __bf16 h2s[2][16][136];
    for (int i = tid; i < 2 * 16 * 136; i += 768) {
        ((__bf16*)h1s)[i] = (__bf16)0.f;
        ((__bf16*)h2s)[i] = (__bf16)0.f;
    }

    // Shared weight array: L1 -> U1 frags for 2 colgroups; L2 -> W2 (gg=0)
    // and U2 (gg=1) frags for 1 colgroup. Union = 24 frags = 96 regs.
    bf16x8 WB[2][3][4];
    f32x4 bq[4];
    uint2 xwv[2][3];                    // L1 only (1-step-ahead prefetch)
    const uint2* xqb = (const uint2*)xw + (size_t)blockIdx.x * 1536
                       + (size_t)(wave * 2) * 64 + lane;

    if (isL1) {
#pragma unroll
        for (int gg = 0; gg < 2; gg++) {
            const int uc = wave * 32 + gg * 16 + lc;
#pragma unroll
            for (int g = 0; g < 3; g++)
#pragma unroll
                for (int kt = 0; kt < 4; kt++) {
                    bf16x8 a;
#pragma unroll
                    for (int j = 0; j < 8; j++)
                        a[j] = (__bf16)U1[(kt * 32 + quad * 8 + j) * G3 + g * 128 + uc];
                    WB[gg][g][kt] = a;
                }
            float b = b1[G3 + 256 + uc];
            bq[gg] = (f32x4){b, b, b, b};
        }
#pragma unroll
        for (int gg = 0; gg < 2; gg++)
#pragma unroll
            for (int g = 0; g < 3; g++)
                xwv[gg][g] = xqb[(size_t)g * 512 + gg * 64];
    } else {
        const int uc = (wave - 4) * 16 + lc;
#pragma unroll
        for (int g = 0; g < 3; g++)
#pragma unroll
            for (int kt = 0; kt < 4; kt++) {
                bf16x8 b, c;
#pragma unroll
                for (int j = 0; j < 8; j++) {
                    int k = (kt * 32 + quad * 8 + j) * G3 + g * 128 + uc;
                    b[j] = (__bf16)W2[k];
                    c[j] = (__bf16)U2[k];
                }
                WB[0][g][kt] = b;   // W2
                WB[1][g][kt] = c;   // U2
            }
        float v0 = b2[uc] + b2[G3 + uc];
        float v1 = b2[128 + uc] + b2[G3 + 128 + uc];
        float v2 = b2[256 + uc];
        float v3 = b2[G3 + 256 + uc];
        bq[0] = (f32x4){v0, v0, v0, v0};   // c2z
        bq[1] = (f32x4){v1, v1, v1, v1};   // c2r
        bq[2] = (f32x4){v2, v2, v2, v2};   // b2ih
        bq[3] = (f32x4){v3, v3, v3, v3};   // b2rh
    }

    float hc[2][4] = {{0, 0, 0, 0}, {0, 0, 0, 0}};  // L1: h1c[gg]; L2: hc[0]=h2c
    __syncthreads();

// Interval n (PAR = n&1): L1 computes h1(n) = f(h1s[PAR^1]); L2 computes
// h2(n-1) = f(h1(n-1)=h1s[PAR^1], h2(n-2)=h2s[PAR^1]). Writes: h1s[PAR],
// h2s[PAR]. Everything read was sealed by the PREVIOUS barrier; one barrier
// per interval, all 12 waves.
#define STEP(T, PAR)                                                           \
    {                                                                          \
        if (isL1) {                                                            \
            _Pragma("unroll") for (int gg = 0; gg < 2; gg++) {                 \
                f32x4 z1  = unpackv(xwv[gg][0]);                               \
                f32x4 r1  = unpackv(xwv[gg][1]);                               \
                f32x4 xh1 = unpackv(xwv[gg][2]);                               \
                if ((T) + 1 < TT) {                                            \
                    _Pragma("unroll") for (int g = 0; g < 3; g++)              \
                        xwv[gg][g] =                                           \
                            xqb[(size_t)((T) + 1) * 24576 + g * 512 + gg * 64];\
                }                                                              \
                f32x4 rh1;                                                     \
                {                                                              \
                    bf16x8 A = *(const bf16x8*)&h1s[PAR ^ 1][lc][quad * 8];    \
                    rh1 = MFMA(A, WB[gg][2][0], bq[gg]);                       \
                    z1  = MFMA(A, WB[gg][0][0], z1);                           \
                    r1  = MFMA(A, WB[gg][1][0], r1);                           \
                }                                                              \
                _Pragma("unroll") for (int kt = 1; kt < 4; kt++) {             \
                    bf16x8 A =                                                 \
                        *(const bf16x8*)&h1s[PAR ^ 1][lc][kt * 32 + quad * 8]; \
                    z1  = MFMA(A, WB[gg][0][kt], z1);                          \
                    r1  = MFMA(A, WB[gg][1][kt], r1);                          \
                    rh1 = MFMA(A, WB[gg][2][kt], rh1);                         \
                }                                                              \
                const int uc = wave * 32 + gg * 16 + lc;                       \
                _Pragma("unroll") for (int i = 0; i < 4; i++) {                \
                    float zf = sigf(z1[i]);                                    \
                    float rf = sigf(r1[i]);                                    \
                    float hh = fmaxf(xh1[i] + rf * rh1[i], 0.f);               \
                    hc[gg][i] = fmaf(zf, hc[gg][i] - hh, hh);                  \
                    h1s[PAR][quad * 4 + i][uc] = (__bf16)hc[gg][i];            \
                }                                                              \
            }                                                                  \
        } else {                                                               \
            f32x4 z2, r2, xh2, rh2;                                            \
            {                                                                  \
                bf16x8 A = *(const bf16x8*)&h1s[PAR ^ 1][lc][quad * 8];        \
                z2  = MFMA(A, WB[0][0][0], bq[0]);                             \
                r2  = MFMA(A, WB[0][1][0], bq[1]);                             \
                xh2 = MFMA(A, WB[0][2][0], bq[2]);                             \
            }                                                                  \
            _Pragma("unroll") for (int kt = 1; kt < 4; kt++) {                 \
                bf16x8 A =                                                     \
                    *(const bf16x8*)&h1s[PAR ^ 1][lc][kt * 32 + quad * 8];     \
                z2  = MFMA(A, WB[0][0][kt], z2);                               \
                r2  = MFMA(A, WB[0][1][kt], r2);                               \
                xh2 = MFMA(A, WB[0][2][kt], xh2);                              \
            }                                                                  \
            {                                                                  \
                bf16x8 A = *(const bf16x8*)&h2s[PAR ^ 1][lc][quad * 8];        \
                rh2 = MFMA(A, WB[1][2][0], bq[3]);                             \
                z2  = MFMA(A, WB[1][0][0], z2);                                \
                r2  = MFMA(A, WB[1][1][0], r2);                                \
            }                                                                  \
            _Pragma("unroll") for (int kt = 1; kt < 4; kt++) {                 \
                bf16x8 A =                                                     \
                    *(const bf16x8*)&h2s[PAR ^ 1][lc][kt * 32 + quad * 8];     \
                z2  = MFMA(A, WB[1][0][kt], z2);                               \
                r2  = MFMA(A, WB[1][1][kt], r2);                               \
                rh2 = MFMA(A, WB[1][2][kt], rh2);                              \
            }                                                                  \
            if ((T) > 0) {                                                     \
                _Pragma("unroll") for (int i = 0; i < 4; i++) {                \
                    float zf = sigf(z2[i]);                                    \
                    float rf = sigf(r2[i]);                                    \
                    float hh = fmaxf(xh2[i] + rf * rh2[i], 0.f);               \
                    hc[0][i] = fmaf(zf, hc[0][i] - hh, hh);                    \
                }                                                              \
            }                                                                  \
            const int uc = (wave - 4) * 16 + lc;                               \
            _Pragma("unroll") for (int i = 0; i < 4; i++)                      \
                h2s[PAR][quad * 4 + i][uc] = (__bf16)hc[0][i];                 \
        }                                                                      \
        asm volatile("s_waitcnt lgkmcnt(0)\n\ts_barrier" ::: "memory");        \
    }

    for (int t = 0; t < TT; t += 2) {
        STEP(t, 0)
        STEP(t + 1, 1)
    }
#undef STEP

    if (isL1) {
        // state1 = h1(TT-1)
#pragma unroll
        for (int gg = 0; gg < 2; gg++) {
            const int uc = wave * 32 + gg * 16 + lc;
#pragma unroll
            for (int i = 0; i < 4; i++) {
                int r = row0 + quad * 4 + i;
                out[32768 + (size_t)r * 128 + uc] = hc[gg][i];
            }
        }
    } else {
        // epilogue: h2(TT-1) from h1(TT-1)=h1s[1] and h2(TT-2)=h2s[1]
        f32x4 z2 = bq[0], r2 = bq[1], xh2 = bq[2], rh2 = bq[3];
#pragma unroll
        for (int kt = 0; kt < 4; kt++) {
            bf16x8 a1 = *(const bf16x8*)&h1s[1][lc][kt * 32 + quad * 8];
            bf16x8 a2 = *(const bf16x8*)&h2s[1][lc][kt * 32 + quad * 8];
            z2  = MFMA(a1, WB[0][0][kt], z2);
            r2  = MFMA(a1, WB[0][1][kt], r2);
            xh2 = MFMA(a1, WB[0][2][kt], xh2);
            z2  = MFMA(a2, WB[1][0][kt], z2);
            r2  = MFMA(a2, WB[1][1][kt], r2);
            rh2 = MFMA(a2, WB[1][2][kt], rh2);
        }
        const int uc = (wave - 4) * 16 + lc;
#pragma unroll
        for (int i = 0; i < 4; i++) {
            float zf = sigf(z2[i]);
            float rf = sigf(r2[i]);
            float hh = fmaxf(xh2[i] + rf * rh2[i], 0.f);
            float h2 = fmaf(zf, hc[0][i] - hh, hh);
            int r = row0 + quad * 4 + i;
            out[(size_t)r * 128 + uc]         = h2;   // x
            out[65536 + (size_t)r * 128 + uc] = h2;   // state2
        }
    }
}

// ---- monolithic fallback (no workspace): R9 structure, W1 in-loop ---------
__global__ __launch_bounds__(512)
__attribute__((amdgpu_waves_per_eu(2, 2)))
void gru_mono(
    const float* __restrict__ x,  const float* __restrict__ W1,
    const float* __restrict__ U1, const float* __restrict__ b1,
    const float* __restrict__ W2, const float* __restrict__ U2,
    const float* __restrict__ b2, float* __restrict__ out)
{
    const int tid  = threadIdx.x;
    const int wave = tid >> 6;
    const int lane = tid & 63;
    const int quad = lane >> 4;
    const int lc   = lane & 15;
    const int row0 = blockIdx.x * 16;
    const int u    = wave * 16 + lc;

    __shared__ __align__(16) __bf16 h1s[2][16][136];
    __shared__ __align__(16) __bf16 h2s[2][16][136];
    for (int i = tid; i < 2 * 16 * 136; i += 512) {
        ((__bf16*)h1s)[i] = (__bf16)0.f;
        ((__bf16*)h2s)[i] = (__bf16)0.f;
    }

    bf16x8 U1B[3][4], W2B[3][4], U2B[3][4], W1B[3][2];
#pragma unroll
    for (int g = 0; g < 3; g++) {
#pragma unroll
        for (int kt = 0; kt < 4; kt++) {
            bf16x8 a, b, c;
#pragma unroll
            for (int j = 0; j < 8; j++) {
                int k = (kt * 32 + quad * 8 + j) * G3 + g * 128 + u;
                a[j] = (__bf16)U1[k];
                b[j] = (__bf16)W2[k];
                c[j] = (__bf16)U2[k];
            }
            U1B[g][kt] = a; W2B[g][kt] = b; U2B[g][kt] = c;
        }
#pragma unroll
        for (int kt = 0; kt < 2; kt++) {
            bf16x8 a;
#pragma unroll
            for (int j = 0; j < 8; j++)
                a[j] = (__bf16)W1[(kt * 32 + quad * 8 + j) * G3 + g * 128 + u];
            W1B[g][kt] = a;
        }
    }

    const float c1z  = b1[u] + b1[G3 + u];
    const float c1r  = b1[128 + u] + b1[G3 + 128 + u];
    const float b1ih = b1[256 + u];
    const float b1rh = b1[G3 + 256 + u];
    const float c2z  = b2[u] + b2[G3 + u];
    const float c2r  = b2[128 + u] + b2[G3 + 128 + u];
    const float b2ih = b2[256 + u];
    const float b2rh = b2[G3 + 256 + u];
    const f32x4 c1zq  = {c1z, c1z, c1z, c1z};
    const f32x4 c1rq  = {c1r, c1r, c1r, c1r};
    const f32x4 b1ihq = {b1ih, b1ih, b1ih, b1ih};
    const f32x4 b1rhq = {b1rh, b1rh, b1rh, b1rh};
    const f32x4 c2zq  = {c2z, c2z, c2z, c2z};
    const f32x4 c2rq  = {c2r, c2r, c2r, c2r};
    const f32x4 b2ihq = {b2ih, b2ih, b2ih, b2ih};
    const f32x4 b2rhq = {b2rh, b2rh, b2rh, b2rh};

    const float* xrow = x + (size_t)(row0 + lc) * (TT * FF) + quad * 8;
    float h1c[4] = {0, 0, 0, 0};
    float h2c[4] = {0, 0, 0, 0};
    __syncthreads();

#define MSTEP(T, PAR)                                                          \
    {                                                                          \
        bf16x8 A1[4];                                                          \
        _Pragma("unroll") for (int kt = 0; kt < 4; kt++)                       \
            A1[kt] = *(const bf16x8*)&h1s[PAR ^ 1][lc][kt * 32 + quad * 8];    \
        const float* px = xrow + (size_t)(T) * FF;                             \
        f32x4 u0 = *(const f32x4*)px;                                          \
        f32x4 u1 = *(const f32x4*)(px + 4);                                    \
        f32x4 u2 = *(const f32x4*)(px + 32);                                   \
        f32x4 u3 = *(const f32x4*)(px + 36);                                   \
        bf16x8 xa0, xa1;                                                       \
        _Pragma("unroll") for (int j = 0; j < 4; j++) {                        \
            xa0[j] = (__bf16)u0[j]; xa0[j + 4] = (__bf16)u1[j];                \
            xa1[j] = (__bf16)u2[j]; xa1[j + 4] = (__bf16)u3[j];                \
        }                                                                      \
        f32x4 z1  = MFMA(xa0, W1B[0][0], c1zq);                                \
        z1        = MFMA(xa1, W1B[0][1], z1);                                  \
        f32x4 r1  = MFMA(xa0, W1B[1][0], c1rq);                                \
        r1        = MFMA(xa1, W1B[1][1], r1);                                  \
        f32x4 xh1 = MFMA(xa0, W1B[2][0], b1ihq);                               \
        xh1       = MFMA(xa1, W1B[2][1], xh1);                                 \
        f32x4 rh1 = MFMA(A1[0], U1B[2][0], b1rhq);                             \
        z1        = MFMA(A1[0], U1B[0][0], z1);                                \
        r1        = MFMA(A1[0], U1B[1][0], r1);                                \
        _Pragma("unroll") for (int kt = 1; kt < 4; kt++) {                     \
            z1  = MFMA(A1[kt], U1B[0][kt], z1);                                \
            r1  = MFMA(A1[kt], U1B[1][kt], r1);                                \
            rh1 = MFMA(A1[kt], U1B[2][kt], rh1);                               \
        }                                                                      \
        _Pragma("unroll") for (int i = 0; i < 4; i++) {                        \
            float zf = sigf(z1[i]);                                            \
            float rf = sigf(r1[i]);                                            \
            float hh = fmaxf(xh1[i] + rf * rh1[i], 0.f);                       \
            h1c[i] = fmaf(zf, h1c[i] - hh, hh);                                \
            h1s[PAR][quad * 4 + i][u] = (__bf16)h1c[i];                        \
        }                                                                      \
        f32x4 z2  = MFMA(A1[0], W2B[0][0], c2zq);                              \
        f32x4 r2  = MFMA(A1[0], W2B[1][0], c2rq);                              \
        f32x4 xh2 = MFMA(A1[0], W2B[2][0], b2ihq);                             \
        _Pragma("unroll") for (int kt = 1; kt < 4; kt++) {                     \
            z2  = MFMA(A1[kt], W2B[0][kt], z2);                                \
            r2  = MFMA(A1[kt], W2B[1][kt], r2);                                \
            xh2 = MFMA(A1[kt], W2B[2][kt], xh2);                               \
        }                                                                      \
        f32x4 rh2;                                                             \
        {                                                                      \
            bf16x8 A2 = *(const bf16x8*)&h2s[PAR][lc][quad * 8];               \
            rh2 = MFMA(A2, U2B[2][0], b2rhq);                                  \
            z2  = MFMA(A2, U2B[0][0], z2);                                     \
            r2  = MFMA(A2, U2B[1][0], r2);                                     \
        }                                                                      \
        _Pragma("unroll") for (int kt = 1; kt < 4; kt++) {                     \
            bf16x8 A2 = *(const bf16x8*)&h2s[PAR][lc][kt * 32 + quad * 8];     \
            z2  = MFMA(A2, U2B[0][kt], z2);                                    \
            r2  = MFMA(A2, U2B[1][kt], r2);                                    \
            rh2 = MFMA(A2, U2B[2][kt], rh2);                                   \
        }                                                                      \
        if ((T) > 0) {                                                         \
            _Pragma("unroll") for (int i = 0; i < 4; i++) {                    \
                float zf = sigf(z2[i]);                                        \
                float rf = sigf(r2[i]);                                        \
                float hh = fmaxf(xh2[i] + rf * rh2[i], 0.f);                   \
                h2c[i] = fmaf(zf, h2c[i] - hh, hh);                            \
            }                                                                  \
        }                                                                      \
        _Pragma("unroll") for (int i = 0; i < 4; i++)                          \
            h2s[PAR ^ 1][quad * 4 + i][u] = (__bf16)h2c[i];                    \
        asm volatile("s_waitcnt lgkmcnt(0)\n\ts_barrier" ::: "memory");        \
    }

    for (int t = 0; t < TT; t += 2) {
        MSTEP(t, 0)
        MSTEP(t + 1, 1)
    }
#undef MSTEP

    {   // epilogue: h2(TT-1)
        f32x4 z2 = c2zq, r2 = c2rq, xh2 = b2ihq, rh2 = b2rhq;
#pragma unroll
        for (int kt = 0; kt < 4; kt++) {
            bf16x8 a1 = *(const bf16x8*)&h1s[1][lc][kt * 32 + quad * 8];
            bf16x8 a2 = *(const bf16x8*)&h2s[0][lc][kt * 32 + quad * 8];
            z2  = MFMA(a1, W2B[0][kt], z2);
            r2  = MFMA(a1, W2B[1][kt], r2);
            xh2 = MFMA(a1, W2B[2][kt], xh2);
            z2  = MFMA(a2, U2B[0][kt], z2);
            r2  = MFMA(a2, U2B[1][kt], r2);
            rh2 = MFMA(a2, U2B[2][kt], rh2);
        }
#pragma unroll
        for (int i = 0; i < 4; i++) {
            float zf = sigf(z2[i]);
            float rf = sigf(r2[i]);
            float hh = fmaxf(xh2[i] + rf * rh2[i], 0.f);
            h2c[i] = fmaf(zf, h2c[i] - hh, hh);
        }
    }

#pragma unroll
    for (int i = 0; i < 4; i++) {
        int r = row0 + quad * 4 + i;
        out[(size_t)r * 128 + u]         = h2c[i];
        out[32768 + (size_t)r * 128 + u] = h1c[i];
        out[65536 + (size_t)r * 128 + u] = h2c[i];
    }
}

extern "C" void kernel_launch(void* const* d_in, const int* in_sizes, int n_in,
                              void* d_out, int out_size, void* d_ws, size_t ws_size,
                              hipStream_t stream) {
    const float* x  = (const float*)d_in[0];
    const float* W1 = (const float*)d_in[1];
    const float* U1 = (const float*)d_in[2];
    const float* b1 = (const float*)d_in[3];
    const float* W2 = (const float*)d_in[4];
    const float* U2 = (const float*)d_in[5];
    const float* b2 = (const float*)d_in[6];
    float* out = (float*)d_out;

    if (ws_size >= XW_BYTES) {
        unsigned short* ws = (unsigned short*)d_ws;
        xw_prepass<<<dim3(16, 256), dim3(256), 0, stream>>>(x, W1, b1, ws);
        gru_persist<<<dim3(16), dim3(768), 0, stream>>>(
            U1, b1, W2, U2, b2, ws, out);
    } else {
        gru_mono<<<dim3(16), dim3(512), 0, stream>>>(
            x, W1, U1, b1, W2, U2, b2, out);
    }
}